// Round 13
// baseline (505.392 us; speedup 1.0000x reference)
//
#include <hip/hip_runtime.h>
#include <hip/hip_bf16.h>
#include <math.h>

#define BATCH 2
#define SEQ   2048
#define EMB   2048
#define NH    16
#define HD    128

typedef __attribute__((ext_vector_type(8))) short short8;
typedef __attribute__((ext_vector_type(8))) _Float16 half8;
typedef __attribute__((ext_vector_type(4))) float floatx4;

__device__ inline void async_load16(const void* g, void* l) {
    __builtin_amdgcn_global_load_lds(
        (const __attribute__((address_space(1))) unsigned int*)g,
        (__attribute__((address_space(3))) unsigned int*)l, 16, 0, 0);
}

__device__ inline unsigned short bf16_bits(float f) {
    __hip_bfloat16 b = __float2bfloat16(f);
    return *(unsigned short*)&b;
}
__device__ inline unsigned short fp16_bits(float f) {
    _Float16 h = (_Float16)f;
    return *(unsigned short*)&h;
}

// ======================= plain bf16 MFMA GEMM (m97 structure) — out projection =======================
#define GT 128
#define GK 32

__global__ __launch_bounds__(256) void gemm_bf16(
    const unsigned short* __restrict__ A,
    const unsigned short* __restrict__ Bt,
    float* __restrict__ C, int M, int N, int K)
{
    __shared__ unsigned short As[GT * GK];
    __shared__ unsigned short Bs[GT * GK];

    const int tid  = threadIdx.x;
    const int w    = tid >> 6;
    const int lane = tid & 63;
    const int wr   = w >> 1, wc = w & 1;
    const int row0 = blockIdx.y * GT;
    const int col0 = blockIdx.x * GT;

    floatx4 acc[4][4];
    #pragma unroll
    for (int i = 0; i < 4; i++)
        #pragma unroll
        for (int j = 0; j < 4; j++)
            acc[i][j] = (floatx4){0.f, 0.f, 0.f, 0.f};

    const int srow  = lane >> 2;
    const int skoff = (lane & 3) * 8;
    const int fm = lane & 15;
    const int fk = (lane >> 4) * 8;

    for (int k0 = 0; k0 < K; k0 += GK) {
        #pragma unroll
        for (int t = 0; t < 2; t++) {
            const int c = w * 2 + t;
            async_load16(A  + (size_t)(row0 + c * 16 + srow) * K + k0 + skoff, (char*)As + c * 1024);
            async_load16(Bt + (size_t)(col0 + c * 16 + srow) * K + k0 + skoff, (char*)Bs + c * 1024);
        }
        __syncthreads();

        short8 af[4], bf[4];
        #pragma unroll
        for (int i = 0; i < 4; i++) {
            af[i] = *(const short8*)&As[(wr * 64 + i * 16 + fm) * GK + fk];
            bf[i] = *(const short8*)&Bs[(wc * 64 + i * 16 + fm) * GK + fk];
        }
        #pragma unroll
        for (int i = 0; i < 4; i++)
            #pragma unroll
            for (int j = 0; j < 4; j++)
                acc[i][j] = __builtin_amdgcn_mfma_f32_16x16x32_bf16(af[i], bf[j], acc[i][j], 0, 0, 0);
        __syncthreads();
    }

    const int quad = lane >> 4;
    #pragma unroll
    for (int i = 0; i < 4; i++)
        #pragma unroll
        for (int j = 0; j < 4; j++) {
            const size_t base = (size_t)(row0 + wr * 64 + i * 16 + quad * 4) * N
                              + col0 + wc * 64 + j * 16 + fm;
            #pragma unroll
            for (int r = 0; r < 4; r++)
                C[base + (size_t)r * N] = acc[i][j][r];
        }
}

// ======================= fused Q+K+V projection: ONE block, shared A staging =======================
// 768 threads = 12 waves: waves 0-3 -> Q-tile (Bq, rms epilogue), 4-7 -> K-tile (Bk,
// rms epilogue + swizzle), 8-11 -> V-tile (Bv, Vt-transpose epilogue). One shared A
// staging per K-step: 32 KB staged for 3 output tiles (vs 40 KB across v16's two
// kernels) and the barrier drain amortized 3x. LDS 38 KB, ~88 VGPR -> 2 blocks/CU
// = 24 waves/CU (6/SIMD, up from 16/CU). XCD 8x8-chunk swizzle keeps each XCD's
// A-panels local to its L2. Grid 512 blocks = 2/CU exactly.
__global__ __launch_bounds__(768) void gemm_qkv_fused(
    const unsigned short* __restrict__ A,
    const unsigned short* __restrict__ Bq, const unsigned short* __restrict__ Bk,
    const unsigned short* __restrict__ Bv,
    const float* __restrict__ q_scale, const float* __restrict__ k_scale,
    unsigned short* __restrict__ Qf, unsigned short* __restrict__ Kf,
    unsigned short* __restrict__ Vt, int K)
{
    __shared__ char smem[38912] __attribute__((aligned(16)));
    unsigned short* As  = (unsigned short*)smem;               // 8 KB
    unsigned short* BsQ = (unsigned short*)(smem + 8192);      // 8 KB
    unsigned short* BsK = (unsigned short*)(smem + 16384);     // 8 KB
    unsigned short* BsV = (unsigned short*)(smem + 24576);     // 8 KB
    float* ws2 = (float*)(smem + 36864);                       // 2 KB [2][2][128]
    typedef unsigned short stage_row[72];
    stage_row* stage0 = (stage_row*)smem;                      // [2][128][72] (V epilogue, aliases dead K-loop bufs)

    const int tid  = threadIdx.x;
    const int w    = tid >> 6;          // 0..11
    const int lane = tid & 63;
    const int role = w >> 2;            // 0=Q, 1=K, 2=V
    const int wq   = w & 3;
    const int wr   = wq >> 1, wc = wq & 1;

    // XCD-chunk swizzle (hw xcd = linear % 8): xcd owns an 8x8 block tile
    const int L   = blockIdx.x;         // 0..511
    const int xcd = L & 7;
    const int idx = L >> 3;             // 0..63
    const int bx  = (xcd & 1) * 8 + (idx & 7);    // 0..15
    const int by  = (xcd >> 1) * 8 + (idx >> 3);  // 0..31
    const int row0 = by * GT;
    const int col0 = bx * GT;

    floatx4 acc[4][4];
    #pragma unroll
    for (int i = 0; i < 4; i++)
        #pragma unroll
        for (int j = 0; j < 4; j++)
            acc[i][j] = (floatx4){0.f, 0.f, 0.f, 0.f};

    const int srow  = lane >> 2;
    const int skoff = (lane & 3) * 8;
    const int fm = lane & 15;
    const int fk = (lane >> 4) * 8;

    for (int k0 = 0; k0 < K; k0 += GK) {
        // 32 chunks of 1 KB (As 8, BsQ 8, BsK 8, BsV 8); waves 0-7 stage 4 each
        if (w < 8) {
            #pragma unroll
            for (int c = 0; c < 4; c++) {
                const int ch  = w * 4 + c;          // 0..31
                const int sub = ch & 7;
                const int base = (ch < 8) ? row0 : col0;
                const size_t off = (size_t)(base + sub * 16 + srow) * K + k0 + skoff;
                switch (ch >> 3) {
                    case 0:  async_load16(A  + off, (char*)As  + sub * 1024); break;
                    case 1:  async_load16(Bq + off, (char*)BsQ + sub * 1024); break;
                    case 2:  async_load16(Bk + off, (char*)BsK + sub * 1024); break;
                    default: async_load16(Bv + off, (char*)BsV + sub * 1024); break;
                }
            }
        }
        __syncthreads();

        const unsigned short* __restrict__ Bs = (role == 0) ? BsQ : (role == 1) ? BsK : BsV;
        half8 af[4], bf[4];
        #pragma unroll
        for (int i = 0; i < 4; i++) {
            af[i] = *(const half8*)&As[(wr * 64 + i * 16 + fm) * GK + fk];
            bf[i] = *(const half8*)&Bs[(wc * 64 + i * 16 + fm) * GK + fk];
        }
        #pragma unroll
        for (int i = 0; i < 4; i++)
            #pragma unroll
            for (int j = 0; j < 4; j++)
                acc[i][j] = __builtin_amdgcn_mfma_f32_16x16x32_f16(af[i], bf[j], acc[i][j], 0, 0, 0);
        __syncthreads();   // final iter: K-loop bufs dead -> V-stage aliasing safe
    }

    const int quad = lane >> 4;
    const int hh = col0 >> 7;   // head index (GT == HD)

    // ---- epilogue part 1 (no barriers inside) ----
    if (role < 2) {
        float sq[4][4];
        #pragma unroll
        for (int i = 0; i < 4; i++)
            #pragma unroll
            for (int r = 0; r < 4; r++) {
                float s2 = 0.f;
                #pragma unroll
                for (int j = 0; j < 4; j++) s2 += acc[i][j][r] * acc[i][j][r];
                s2 += __shfl_xor(s2, 1);
                s2 += __shfl_xor(s2, 2);
                s2 += __shfl_xor(s2, 4);
                s2 += __shfl_xor(s2, 8);
                sq[i][r] = s2;
            }
        if (fm == 0) {
            #pragma unroll
            for (int i = 0; i < 4; i++)
                #pragma unroll
                for (int r = 0; r < 4; r++)
                    ws2[(role * 2 + wc) * 128 + wr * 64 + i * 16 + quad * 4 + r] = sq[i][r];
        }
    } else {
        #pragma unroll
        for (int i = 0; i < 4; i++)
            #pragma unroll
            for (int r = 0; r < 4; r++) {
                const int key = i * 16 + quad * 4 + r;           // 0..63
                #pragma unroll
                for (int j = 0; j < 4; j++) {
                    const int d = wc * 64 + j * 16 + fm;
                    stage0[wr * 128 + d][key] = fp16_bits(acc[i][j][r]);
                }
            }
    }
    __syncthreads();

    // ---- epilogue part 2 ----
    if (role < 2) {
        const float* __restrict__ scale = role ? k_scale : q_scale;
        unsigned short* __restrict__ o = role ? Kf : Qf;
        float scv[4];
        #pragma unroll
        for (int j = 0; j < 4; j++) scv[j] = scale[wc * 64 + j * 16 + fm];

        #pragma unroll
        for (int i = 0; i < 4; i++)
            #pragma unroll
            for (int r = 0; r < 4; r++) {
                const int lrow = wr * 64 + i * 16 + quad * 4 + r;
                const int row  = row0 + lrow;            // global m = b*SEQ + s
                const int bb = row >> 11, s = row & 2047;
                const float inv = rsqrtf((ws2[role * 2 * 128 + lrow] + ws2[(role * 2 + 1) * 128 + lrow]) * (1.0f / HD) + 1e-6f);
                const size_t ob = ((size_t)(bb * NH + hh) * SEQ + s) * 128;
                #pragma unroll
                for (int j = 0; j < 4; j++) {
                    const int d = wc * 64 + j * 16 + fm;
                    const float val = acc[i][j][r] * inv * scv[j];
                    const int dd = role ? ((((d >> 3) ^ (s & 15)) << 3) | (d & 7)) : d;
                    o[ob + dd] = fp16_bits(val);
                }
            }
    } else {
        const int b  = row0 >> 11;
        const int bh = b * NH + hh;
        const int kt_base = (row0 & 2047) >> 6;
        const int vtid = tid & 255;          // 0..255 within the V wave-group
        const int d = vtid >> 1, half_ = vtid & 1;
        #pragma unroll
        for (int kt = 0; kt < 2; kt++) {
            const size_t ob = ((size_t)(bh * 32 + kt_base + kt)) * 8192 + (size_t)d * 64;
            #pragma unroll
            for (int cc = 0; cc < 4; cc++) {
                const int cs = half_ * 4 + cc;
                const int kb = (cs ^ (d & 7)) << 3;
                *(short8*)&Vt[ob + cs * 8] = *(const short8*)&stage0[kt * 128 + d][kb];
            }
        }
    }
}

// ======================= weight prep + x cast, single dispatch =======================
__global__ __launch_bounds__(256) void prep_all(
    const float* __restrict__ wq, const float* __restrict__ wk,
    const float* __restrict__ wv, const float* __restrict__ wo,
    const float* __restrict__ x,
    unsigned short* __restrict__ wqF, unsigned short* __restrict__ wkF,
    unsigned short* __restrict__ wvF, unsigned short* __restrict__ woT,
    unsigned short* __restrict__ xf)
{
    __shared__ float tile[32][33];
    const int z = blockIdx.z;
    const int tx = threadIdx.x, ty = threadIdx.y;

    if (z == 4) {
        const int blk = blockIdx.y * 64 + blockIdx.x;
        const size_t base = (size_t)blk * 2048 + (ty * 32 + tx) * 8;
        float4 a = *(const float4*)&x[base];
        float4 b = *(const float4*)&x[base + 4];
        ushort4 ha, hb;
        ha.x = fp16_bits(a.x); ha.y = fp16_bits(a.y); ha.z = fp16_bits(a.z); ha.w = fp16_bits(a.w);
        hb.x = fp16_bits(b.x); hb.y = fp16_bits(b.y); hb.z = fp16_bits(b.z); hb.w = fp16_bits(b.w);
        *(ushort4*)&xf[base] = ha;
        *(ushort4*)&xf[base + 4] = hb;
        return;
    }

    const float* __restrict__ W = (z == 0) ? wq : (z == 1) ? wk : (z == 2) ? wv : wo;
    const int k0 = blockIdx.y * 32, n0 = blockIdx.x * 32;
    #pragma unroll
    for (int i = 0; i < 4; i++)
        tile[ty + i * 8][tx] = W[(size_t)(k0 + ty + i * 8) * 2048 + n0 + tx];
    __syncthreads();
    if (z < 3) {
        unsigned short* __restrict__ t = (z == 0) ? wqF : (z == 1) ? wkF : wvF;
        #pragma unroll
        for (int i = 0; i < 4; i++)
            t[(size_t)(n0 + ty + i * 8) * 2048 + k0 + tx] = fp16_bits(tile[tx][ty + i * 8]);
    } else {
        #pragma unroll
        for (int i = 0; i < 4; i++)
            woT[(size_t)(n0 + ty + i * 8) * 2048 + k0 + tx] = bf16_bits(tile[tx][ty + i * 8]);
    }
}

// ======================= MFMA flash attention v14 + XCD head-grouping =======================
// v4's EXACT schedule (512 threads = 8 waves, ATQ=256/32 rows per wave, ATK=64,
// double-buffered KV staging, prefetch at tile start, ONE barrier per tile,
// 256 blocks = 1/CU) with fp16 single-term Q/K/V/P. ONLY change vs round-10/11:
// blockIdx remap so XCD x owns heads 4x..4x+3 entirely (4 MB K+Vt = one L2) --
// kills the 8x cross-XCD K/V re-fetch. Pure index remap; schedule untouched.
#define ATQ 256
#define ATK 64

__global__ __launch_bounds__(512, 1) void attn14(
    const unsigned short* __restrict__ Qf, const unsigned short* __restrict__ Kf,
    const unsigned short* __restrict__ Vt, __hip_bfloat16* __restrict__ AO)
{
    __shared__ unsigned short Ks[2][ATK * 128];    // 32 KB  [key][d'] (chunk ^= key&15)
    __shared__ unsigned short Vts[2][HD * 64];     // 32 KB  [d][key'] (chunk ^= d&7)
    __shared__ unsigned short Ps[ATQ * 64];        // 32 KB  P[row][key'] (chunk ^= row&7)

    const int tid  = threadIdx.x;
    const int w    = tid >> 6;        // 0..7
    const int lane = tid & 63;
    const int quad = lane >> 4;
    const int fm   = lane & 15;

    // XCD head-grouping: hw xcd = linear % 8; xcd owns heads 4x..4x+3 (all q-blocks)
    const int L   = blockIdx.x;       // 0..255
    const int xcd = L & 7;
    const int g   = L >> 3;           // 0..31
    const int bh  = xcd * 4 + (g & 3);
    const int q0  = (g >> 2) * ATQ;
    const int b = bh >> 4, h = bh & 15;

    const size_t hbase = (size_t)(b * NH + h) * SEQ;

    // ---- Q fragments (fp16); wave owns rows w*32..w*32+31 ----
    half8 qf[2][4];
    #pragma unroll
    for (int i = 0; i < 2; i++) {
        const size_t row = hbase + q0 + w * 32 + i * 16 + fm;
        #pragma unroll
        for (int kc = 0; kc < 4; kc++)
            qf[i][kc] = *(const half8*)&Qf[row * 128 + kc * 32 + quad * 8];
    }

    floatx4 oacc[2][8];
    #pragma unroll
    for (int i = 0; i < 2; i++)
        #pragma unroll
        for (int df = 0; df < 8; df++)
            oacc[i][df] = (floatx4){0.f, 0.f, 0.f, 0.f};
    float m_[2][4], l_[2][4];
    #pragma unroll
    for (int i = 0; i < 2; i++)
        #pragma unroll
        for (int r = 0; r < 4; r++) { m_[i][r] = -1e30f; l_[i][r] = 0.f; }

    const unsigned short* gk0  = Kf + hbase * 128;
    const unsigned short* gvt0 = Vt + (size_t)bh * 32 * 8192;

    // staging: 32 chunks of 1 KB (Ks 16, Vts 16); wave w -> chunks w*4..w*4+3
    const int ch0 = w * 4;

    // ---- prologue: stage tile 0 into buffer 0 ----
    #pragma unroll
    for (int c = 0; c < 4; c++) {
        const int ch = ch0 + c;
        const size_t go = (size_t)(ch & 15) * 512 + lane * 8;
        if (ch < 16) async_load16(gk0  + go, (char*)Ks[0]  + ch * 1024);
        else         async_load16(gvt0 + go, (char*)Vts[0] + (ch - 16) * 1024);
    }
    __syncthreads();   // drain: tile 0 staged

    for (int ktile = 0; ktile < SEQ / ATK; ktile++) {
        const int cur = ktile & 1;

        // ---- prefetch tile t+1 into other buffer (drained by end-of-tile barrier) ----
        if (ktile + 1 < SEQ / ATK) {
            const unsigned short* gk  = gk0  + (size_t)(ktile + 1) * ATK * 128;
            const unsigned short* gvt = gvt0 + (size_t)(ktile + 1) * 8192;
            #pragma unroll
            for (int c = 0; c < 4; c++) {
                const int ch = ch0 + c;
                const size_t go = (size_t)(ch & 15) * 512 + lane * 8;
                if (ch < 16) async_load16(gk  + go, (char*)Ks[1 - cur]  + ch * 1024);
                else         async_load16(gvt + go, (char*)Vts[1 - cur] + (ch - 16) * 1024);
            }
        }

        // ---- S = Q K^T (single-term fp16) from buffer cur ----
        floatx4 sacc[2][4];
        #pragma unroll
        for (int i = 0; i < 2; i++)
            #pragma unroll
            for (int jf = 0; jf < 4; jf++)
                sacc[i][jf] = (floatx4){0.f, 0.f, 0.f, 0.f};
        #pragma unroll
        for (int kc = 0; kc < 4; kc++)
            #pragma unroll
            for (int jf = 0; jf < 4; jf++) {
                const int koff = (jf * 16 + fm) * 128 + (((kc * 4 + quad) ^ fm) << 3);
                half8 k8 = *(const half8*)&Ks[cur][koff];
                #pragma unroll
                for (int i = 0; i < 2; i++)
                    sacc[i][jf] = __builtin_amdgcn_mfma_f32_16x16x32_f16(qf[i][kc], k8, sacc[i][jf], 0, 0, 0);
            }

        // ---- online softmax (registers) ----
        float alpha_[2][4];
        #pragma unroll
        for (int i = 0; i < 2; i++)
            #pragma unroll
            for (int r = 0; r < 4; r++) {
                float mx = fmaxf(fmaxf(sacc[i][0][r], sacc[i][1][r]),
                                 fmaxf(sacc[i][2][r], sacc[i][3][r]));
                mx = fmaxf(mx, __shfl_xor(mx, 1));
                mx = fmaxf(mx, __shfl_xor(mx, 2));
                mx = fmaxf(mx, __shfl_xor(mx, 4));
                mx = fmaxf(mx, __shfl_xor(mx, 8));
                const float mold = m_[i][r];
                const float mnew = fmaxf(mold, mx);
                const float al = __expf(mold - mnew);
                m_[i][r] = mnew;
                alpha_[i][r] = al;
                float rs = 0.f;
                #pragma unroll
                for (int jf = 0; jf < 4; jf++) {
                    float p = __expf(sacc[i][jf][r] - mnew);
                    sacc[i][jf][r] = p;
                    rs += p;
                }
                rs += __shfl_xor(rs, 1);
                rs += __shfl_xor(rs, 2);
                rs += __shfl_xor(rs, 4);
                rs += __shfl_xor(rs, 8);
                l_[i][r] = l_[i][r] * al + rs;
            }
        #pragma unroll
        for (int i = 0; i < 2; i++)
            #pragma unroll
            for (int df = 0; df < 8; df++)
                #pragma unroll
                for (int r = 0; r < 4; r++)
                    oacc[i][df][r] *= alpha_[i][r];

        // ---- P -> fp16 into Ps (own rows; wave-local ordering, no barrier) ----
        #pragma unroll
        for (int i = 0; i < 2; i++)
            #pragma unroll
            for (int jf = 0; jf < 4; jf++)
                #pragma unroll
                for (int r = 0; r < 4; r++) {
                    const int row = w * 32 + i * 16 + quad * 4 + r;
                    const int chunk = jf * 2 + (fm >> 3);
                    const int colp = ((chunk ^ (row & 7)) << 3) | (fm & 7);
                    Ps[row * 64 + colp] = fp16_bits(sacc[i][jf][r]);
                }

        // ---- O += P V from buffer cur (fp16) ----
        #pragma unroll
        for (int kc2 = 0; kc2 < 2; kc2++) {
            half8 ap[2];
            #pragma unroll
            for (int i = 0; i < 2; i++) {
                const int row = w * 32 + i * 16 + fm;
                ap[i] = *(const half8*)&Ps[row * 64 + (((kc2 * 4 + quad) ^ (row & 7)) << 3)];
            }
            #pragma unroll
            for (int df = 0; df < 8; df++) {
                const int d = df * 16 + fm;
                half8 bv = *(const half8*)&Vts[cur][d * 64 + (((kc2 * 4 + quad) ^ (d & 7)) << 3)];
                #pragma unroll
                for (int i = 0; i < 2; i++)
                    oacc[i][df] = __builtin_amdgcn_mfma_f32_16x16x32_f16(ap[i], bv, oacc[i][df], 0, 0, 0);
            }
        }

        // single barrier per tile: drains prefetch + protects buffer swap
        __syncthreads();
    }

    // ---- epilogue: AO bf16 [b,s,h,d] ----
    const size_t obase = ((size_t)b * SEQ * NH + h) * HD;
    const size_t rstr = (size_t)NH * HD;
    float linv[2][4];
    #pragma unroll
    for (int i = 0; i < 2; i++)
        #pragma unroll
        for (int r = 0; r < 4; r++) linv[i][r] = 1.0f / l_[i][r];
    #pragma unroll
    for (int i = 0; i < 2; i++)
        #pragma unroll
        for (int df = 0; df < 8; df++)
            #pragma unroll
            for (int r = 0; r < 4; r++) {
                const int row = q0 + w * 32 + i * 16 + quad * 4 + r;
                const int d = df * 16 + fm;
                AO[obase + (size_t)row * rstr + d] = __float2bfloat16(oacc[i][df][r] * linv[i][r]);
            }
}

// ======================= launch =======================
extern "C" void kernel_launch(void* const* d_in, const int* in_sizes, int n_in,
                              void* d_out, int out_size, void* d_ws, size_t ws_size,
                              hipStream_t stream) {
    const float* x  = (const float*)d_in[0];
    const float* wq = (const float*)d_in[1];
    const float* wk = (const float*)d_in[2];
    const float* wv = (const float*)d_in[3];
    const float* wo = (const float*)d_in[4];
    const float* q_scale = (const float*)d_in[5];
    const float* k_scale = (const float*)d_in[6];
    float* out = (float*)d_out;

    const size_t T = (size_t)BATCH * SEQ * NH * HD;   // 8388608
    const size_t W = (size_t)EMB * NH * HD;           // 4194304

    unsigned short* xf   = (unsigned short*)d_ws;     // fp16 x
    unsigned short* aob  = xf + T;                    // bf16 attn out
    unsigned short* Qf   = aob + T;                   // fp16 Q (head-major)
    unsigned short* Kf   = Qf + T;                    // fp16 K (head-major, swizzled)
    unsigned short* Vtb  = Kf + T;                    // fp16 Vt tiles
    unsigned short* wqF  = Vtb + T;                   // fp16 [n][k]
    unsigned short* wkF  = wqF + W;
    unsigned short* wvF  = wkF + W;
    unsigned short* woT  = wvF + W;                   // bf16 [n][k]

    const int M = BATCH * SEQ;   // 4096
    const int N = NH * HD;       // 2048
    const int K = EMB;           // 2048

    // weight transposes (wq/wk/wv->fp16, wo->bf16) + x->fp16 cast, one dispatch
    prep_all<<<dim3(64, 64, 5), dim3(32, 8), 0, stream>>>(
        wq, wk, wv, wo, x, wqF, wkF, wvF, woT, xf);

    // fused Q+K+V projection: one block computes all three tiles from shared A staging
    gemm_qkv_fused<<<512, 768, 0, stream>>>(
        xf, wqF, wkF, wvF, q_scale, k_scale, Qf, Kf, Vtb, K);

    attn14<<<256, 512, 0, stream>>>(Qf, Kf, Vtb, (__hip_bfloat16*)aob);

    gemm_bf16<<<dim3(EMB / GT, M / GT), 256, 0, stream>>>(aob, woT, out, M, EMB, NH * HD);
}

// Round 14
// 463.259 us; speedup vs baseline: 1.0909x; 1.0909x over previous
//
#include <hip/hip_runtime.h>
#include <hip/hip_bf16.h>
#include <math.h>

#define BATCH 2
#define SEQ   2048
#define EMB   2048
#define NH    16
#define HD    128

typedef __attribute__((ext_vector_type(8))) short short8;
typedef __attribute__((ext_vector_type(8))) _Float16 half8;
typedef __attribute__((ext_vector_type(4))) float floatx4;

__device__ inline void async_load16(const void* g, void* l) {
    __builtin_amdgcn_global_load_lds(
        (const __attribute__((address_space(1))) unsigned int*)g,
        (__attribute__((address_space(3))) unsigned int*)l, 16, 0, 0);
}

__device__ inline unsigned short bf16_bits(float f) {
    __hip_bfloat16 b = __float2bfloat16(f);
    return *(unsigned short*)&b;
}
__device__ inline unsigned short fp16_bits(float f) {
    _Float16 h = (_Float16)f;
    return *(unsigned short*)&h;
}

// ======================= out-projection GEMM (m97 structure, bf16) + XCD swizzle =======================
// Grid 512 blocks (16 x-cols, 32 y-rows) -- same shape as gemm_qk_fused, so the same
// validated 8x8 XCD chunk remap applies: each XCD owns an 8x8 block tile -> A/B
// panels stay in its own L2 instead of being fetched by all 8 XCDs.
#define GT 128
#define GK 32

__global__ __launch_bounds__(256) void gemm_out(
    const unsigned short* __restrict__ A,
    const unsigned short* __restrict__ Bt,
    float* __restrict__ C, int M, int N, int K)
{
    __shared__ unsigned short As[GT * GK];
    __shared__ unsigned short Bs[GT * GK];

    const int tid  = threadIdx.x;
    const int w    = tid >> 6;
    const int lane = tid & 63;
    const int wr   = w >> 1, wc = w & 1;

    // XCD-chunk swizzle (hw xcd = linear % 8): xcd owns an 8x8 block tile
    const int L   = blockIdx.x;         // 0..511
    const int xcd = L & 7;
    const int idx = L >> 3;             // 0..63
    const int bx  = (xcd & 1) * 8 + (idx & 7);    // 0..15
    const int by  = (xcd >> 1) * 8 + (idx >> 3);  // 0..31
    const int row0 = by * GT;
    const int col0 = bx * GT;

    floatx4 acc[4][4];
    #pragma unroll
    for (int i = 0; i < 4; i++)
        #pragma unroll
        for (int j = 0; j < 4; j++)
            acc[i][j] = (floatx4){0.f, 0.f, 0.f, 0.f};

    const int srow  = lane >> 2;
    const int skoff = (lane & 3) * 8;
    const int fm = lane & 15;
    const int fk = (lane >> 4) * 8;

    for (int k0 = 0; k0 < K; k0 += GK) {
        #pragma unroll
        for (int t = 0; t < 2; t++) {
            const int c = w * 2 + t;
            async_load16(A  + (size_t)(row0 + c * 16 + srow) * K + k0 + skoff, (char*)As + c * 1024);
            async_load16(Bt + (size_t)(col0 + c * 16 + srow) * K + k0 + skoff, (char*)Bs + c * 1024);
        }
        __syncthreads();

        short8 af[4], bf[4];
        #pragma unroll
        for (int i = 0; i < 4; i++) {
            af[i] = *(const short8*)&As[(wr * 64 + i * 16 + fm) * GK + fk];
            bf[i] = *(const short8*)&Bs[(wc * 64 + i * 16 + fm) * GK + fk];
        }
        #pragma unroll
        for (int i = 0; i < 4; i++)
            #pragma unroll
            for (int j = 0; j < 4; j++)
                acc[i][j] = __builtin_amdgcn_mfma_f32_16x16x32_bf16(af[i], bf[j], acc[i][j], 0, 0, 0);
        __syncthreads();
    }

    const int quad = lane >> 4;
    #pragma unroll
    for (int i = 0; i < 4; i++)
        #pragma unroll
        for (int j = 0; j < 4; j++) {
            const size_t base = (size_t)(row0 + wr * 64 + i * 16 + quad * 4) * N
                              + col0 + wc * 64 + j * 16 + fm;
            #pragma unroll
            for (int r = 0; r < 4; r++)
                C[base + (size_t)r * N] = acc[i][j][r];
        }
}

// ======================= fused Q+K projection: ONE block, shared A staging =======================
// 512 threads = 8 waves: waves 0-3 compute the Q-tile (Bq), waves 4-7 the K-tile (Bk),
// from ONE shared A staging per K-step (24 KB staged for 2 output tiles -> barrier
// drain amortized 2x vs separate blocks). LDS 26 KB, ~90 VGPR -> 2 blocks/CU.
// XCD 8x8-chunk swizzle keeps each XCD's A-panels local to its L2.
__global__ __launch_bounds__(512) void gemm_qk_fused(
    const unsigned short* __restrict__ A,
    const unsigned short* __restrict__ Bq, const unsigned short* __restrict__ Bk,
    const float* __restrict__ q_scale, const float* __restrict__ k_scale,
    unsigned short* __restrict__ Qf, unsigned short* __restrict__ Kf, int K)
{
    __shared__ unsigned short As[GT * GK];    // 8 KB (shared by both halves)
    __shared__ unsigned short BsQ[GT * GK];   // 8 KB
    __shared__ unsigned short BsK[GT * GK];   // 8 KB
    __shared__ float ws2[2][2][GT];           // 2 KB

    const int tid  = threadIdx.x;
    const int w    = tid >> 6;          // 0..7
    const int lane = tid & 63;
    const int half = w >> 2;            // 0 = Q, 1 = K
    const int wq   = w & 3;
    const int wr   = wq >> 1, wc = wq & 1;

    // XCD-chunk swizzle (hw xcd = linear % 8): xcd owns an 8x8 block tile
    const int L   = blockIdx.x;         // 0..511
    const int xcd = L & 7;
    const int idx = L >> 3;             // 0..63
    const int bx  = (xcd & 1) * 8 + (idx & 7);    // 0..15
    const int by  = (xcd >> 1) * 8 + (idx >> 3);  // 0..31
    const int row0 = by * GT;
    const int col0 = bx * GT;

    floatx4 acc[4][4];
    #pragma unroll
    for (int i = 0; i < 4; i++)
        #pragma unroll
        for (int j = 0; j < 4; j++)
            acc[i][j] = (floatx4){0.f, 0.f, 0.f, 0.f};

    const int srow  = lane >> 2;
    const int skoff = (lane & 3) * 8;
    const int fm = lane & 15;
    const int fk = (lane >> 4) * 8;

    for (int k0 = 0; k0 < K; k0 += GK) {
        // 24 chunks of 1 KB (As 8, BsQ 8, BsK 8); wave w -> chunks w*3..w*3+2
        #pragma unroll
        for (int c = 0; c < 3; c++) {
            const int ch  = w * 3 + c;          // 0..23
            const int sub = ch & 7;
            const int base = (ch < 8) ? row0 : col0;
            const size_t off = (size_t)(base + sub * 16 + srow) * K + k0 + skoff;
            if (ch < 8)       async_load16(A  + off, (char*)As  + sub * 1024);
            else if (ch < 16) async_load16(Bq + off, (char*)BsQ + sub * 1024);
            else              async_load16(Bk + off, (char*)BsK + sub * 1024);
        }
        __syncthreads();

        const unsigned short* __restrict__ Bs = half ? BsK : BsQ;
        half8 af[4], bf[4];
        #pragma unroll
        for (int i = 0; i < 4; i++) {
            af[i] = *(const half8*)&As[(wr * 64 + i * 16 + fm) * GK + fk];
            bf[i] = *(const half8*)&Bs[(wc * 64 + i * 16 + fm) * GK + fk];
        }
        #pragma unroll
        for (int i = 0; i < 4; i++)
            #pragma unroll
            for (int j = 0; j < 4; j++)
                acc[i][j] = __builtin_amdgcn_mfma_f32_16x16x32_f16(af[i], bf[j], acc[i][j], 0, 0, 0);
        __syncthreads();
    }

    // ---- fused epilogue: per-half RMSNorm + relayout (fp16 out) ----
    const int quad = lane >> 4;
    const float* __restrict__ scale = half ? k_scale : q_scale;
    unsigned short* __restrict__ o = half ? Kf : Qf;
    const int hh = col0 >> 7;   // head index (GT == HD)

    float sq[4][4];
    #pragma unroll
    for (int i = 0; i < 4; i++)
        #pragma unroll
        for (int r = 0; r < 4; r++) {
            float s2 = 0.f;
            #pragma unroll
            for (int j = 0; j < 4; j++) s2 += acc[i][j][r] * acc[i][j][r];
            s2 += __shfl_xor(s2, 1);
            s2 += __shfl_xor(s2, 2);
            s2 += __shfl_xor(s2, 4);
            s2 += __shfl_xor(s2, 8);
            sq[i][r] = s2;
        }
    if (fm == 0) {
        #pragma unroll
        for (int i = 0; i < 4; i++)
            #pragma unroll
            for (int r = 0; r < 4; r++)
                ws2[half][wc][wr * 64 + i * 16 + quad * 4 + r] = sq[i][r];
    }
    __syncthreads();

    float scv[4];
    #pragma unroll
    for (int j = 0; j < 4; j++) scv[j] = scale[wc * 64 + j * 16 + fm];

    #pragma unroll
    for (int i = 0; i < 4; i++)
        #pragma unroll
        for (int r = 0; r < 4; r++) {
            const int lrow = wr * 64 + i * 16 + quad * 4 + r;
            const int row  = row0 + lrow;            // global m = b*SEQ + s
            const int bb = row >> 11, s = row & 2047;
            const float inv = rsqrtf((ws2[half][0][lrow] + ws2[half][1][lrow]) * (1.0f / HD) + 1e-6f);
            const size_t ob = ((size_t)(bb * NH + hh) * SEQ + s) * 128;
            #pragma unroll
            for (int j = 0; j < 4; j++) {
                const int d = wc * 64 + j * 16 + fm;
                const float val = acc[i][j][r] * inv * scv[j];
                const int dd = half ? ((((d >> 3) ^ (s & 15)) << 3) | (d & 7)) : d;
                o[ob + dd] = fp16_bits(val);
            }
        }
}

// ======================= fp16 V projection GEMM + fused Vt epilogue (fp16 out) =======================
__global__ __launch_bounds__(256) void gemm_v_vt(
    const unsigned short* __restrict__ A,
    const unsigned short* __restrict__ Bt,
    unsigned short* __restrict__ Vt, int K)
{
    __shared__ char smem[2 * 128 * 72 * 2] __attribute__((aligned(16)));  // 36 KB
    unsigned short* As = (unsigned short*)smem;                // 8 KB (K-loop)
    unsigned short* Bs = (unsigned short*)(smem + 8192);       // 8 KB (K-loop)
    typedef unsigned short stage_row[72];
    stage_row* stage0 = (stage_row*)smem;                      // [2][128][72] (epilogue)

    const int tid  = threadIdx.x;
    const int w    = tid >> 6;
    const int lane = tid & 63;
    const int wr   = w >> 1, wc = w & 1;
    const int row0 = blockIdx.y * GT;
    const int col0 = blockIdx.x * GT;

    floatx4 acc[4][4];
    #pragma unroll
    for (int i = 0; i < 4; i++)
        #pragma unroll
        for (int j = 0; j < 4; j++)
            acc[i][j] = (floatx4){0.f, 0.f, 0.f, 0.f};

    const int srow  = lane >> 2;
    const int skoff = (lane & 3) * 8;
    const int fm = lane & 15;
    const int fk = (lane >> 4) * 8;

    for (int k0 = 0; k0 < K; k0 += GK) {
        #pragma unroll
        for (int t = 0; t < 2; t++) {
            const int c = w * 2 + t;
            async_load16(A  + (size_t)(row0 + c * 16 + srow) * K + k0 + skoff, (char*)As + c * 1024);
            async_load16(Bt + (size_t)(col0 + c * 16 + srow) * K + k0 + skoff, (char*)Bs + c * 1024);
        }
        __syncthreads();

        half8 af[4], bf[4];
        #pragma unroll
        for (int i = 0; i < 4; i++) {
            af[i] = *(const half8*)&As[(wr * 64 + i * 16 + fm) * GK + fk];
            bf[i] = *(const half8*)&Bs[(wc * 64 + i * 16 + fm) * GK + fk];
        }
        #pragma unroll
        for (int i = 0; i < 4; i++)
            #pragma unroll
            for (int j = 0; j < 4; j++)
                acc[i][j] = __builtin_amdgcn_mfma_f32_16x16x32_f16(af[i], bf[j], acc[i][j], 0, 0, 0);
        __syncthreads();   // also makes As/Bs dead -> stage aliasing safe
    }

    // ---- fused epilogue: transpose to Vt layout (fp16) ----
    const int quad = lane >> 4;
    const int b  = row0 >> 11;            // batch (128 | 2048, no straddle)
    const int h  = col0 >> 7;             // head (GT == HD)
    const int bh = b * NH + h;
    const int kt_base = (row0 & 2047) >> 6;

    #pragma unroll
    for (int i = 0; i < 4; i++)
        #pragma unroll
        for (int r = 0; r < 4; r++) {
            const int key = i * 16 + quad * 4 + r;           // 0..63
            #pragma unroll
            for (int j = 0; j < 4; j++) {
                const int d = wc * 64 + j * 16 + fm;
                stage0[wr * 128 + d][key] = fp16_bits(acc[i][j][r]);
            }
        }
    __syncthreads();

    const int d = tid >> 1, half = tid & 1;
    #pragma unroll
    for (int kt = 0; kt < 2; kt++) {
        const size_t ob = ((size_t)(bh * 32 + kt_base + kt)) * 8192 + (size_t)d * 64;
        #pragma unroll
        for (int cc = 0; cc < 4; cc++) {
            const int cs = half * 4 + cc;
            const int kb = (cs ^ (d & 7)) << 3;
            *(short8*)&Vt[ob + cs * 8] = *(const short8*)&stage0[kt * 128 + d][kb];
        }
    }
}

// ======================= weight prep + x cast, single dispatch =======================
__global__ __launch_bounds__(256) void prep_all(
    const float* __restrict__ wq, const float* __restrict__ wk,
    const float* __restrict__ wv, const float* __restrict__ wo,
    const float* __restrict__ x,
    unsigned short* __restrict__ wqF, unsigned short* __restrict__ wkF,
    unsigned short* __restrict__ wvF, unsigned short* __restrict__ woT,
    unsigned short* __restrict__ xf)
{
    __shared__ float tile[32][33];
    const int z = blockIdx.z;
    const int tx = threadIdx.x, ty = threadIdx.y;

    if (z == 4) {
        const int blk = blockIdx.y * 64 + blockIdx.x;
        const size_t base = (size_t)blk * 2048 + (ty * 32 + tx) * 8;
        float4 a = *(const float4*)&x[base];
        float4 b = *(const float4*)&x[base + 4];
        ushort4 ha, hb;
        ha.x = fp16_bits(a.x); ha.y = fp16_bits(a.y); ha.z = fp16_bits(a.z); ha.w = fp16_bits(a.w);
        hb.x = fp16_bits(b.x); hb.y = fp16_bits(b.y); hb.z = fp16_bits(b.z); hb.w = fp16_bits(b.w);
        *(ushort4*)&xf[base] = ha;
        *(ushort4*)&xf[base + 4] = hb;
        return;
    }

    const float* __restrict__ W = (z == 0) ? wq : (z == 1) ? wk : (z == 2) ? wv : wo;
    const int k0 = blockIdx.y * 32, n0 = blockIdx.x * 32;
    #pragma unroll
    for (int i = 0; i < 4; i++)
        tile[ty + i * 8][tx] = W[(size_t)(k0 + ty + i * 8) * 2048 + n0 + tx];
    __syncthreads();
    if (z < 3) {
        unsigned short* __restrict__ t = (z == 0) ? wqF : (z == 1) ? wkF : wvF;
        #pragma unroll
        for (int i = 0; i < 4; i++)
            t[(size_t)(n0 + ty + i * 8) * 2048 + k0 + tx] = fp16_bits(tile[tx][ty + i * 8]);
    } else {
        #pragma unroll
        for (int i = 0; i < 4; i++)
            woT[(size_t)(n0 + ty + i * 8) * 2048 + k0 + tx] = bf16_bits(tile[tx][ty + i * 8]);
    }
}

// ======================= MFMA flash attention v14 (verbatim round-11/12, linear blockIdx) =======================
// v4's EXACT structure (512 threads = 8 waves, ATQ=256/32 rows per wave, ATK=64,
// double-buffered KV staging, prefetch at tile start, ONE barrier per tile,
// grid (8,32) = 256 blocks, 1 block/CU) with fp16 single-term Q/K/V/P.
// NO setprio / defer-max / blockIdx remap: all schedule & mapping perturbations
// regressed (v5-v9, v17 head-grouping thrashed L2).
#define ATQ 256
#define ATK 64

__global__ __launch_bounds__(512, 1) void attn14(
    const unsigned short* __restrict__ Qf, const unsigned short* __restrict__ Kf,
    const unsigned short* __restrict__ Vt, __hip_bfloat16* __restrict__ AO)
{
    __shared__ unsigned short Ks[2][ATK * 128];    // 32 KB  [key][d'] (chunk ^= key&15)
    __shared__ unsigned short Vts[2][HD * 64];     // 32 KB  [d][key'] (chunk ^= d&7)
    __shared__ unsigned short Ps[ATQ * 64];        // 32 KB  P[row][key'] (chunk ^= row&7)

    const int tid  = threadIdx.x;
    const int w    = tid >> 6;        // 0..7
    const int lane = tid & 63;
    const int quad = lane >> 4;
    const int fm   = lane & 15;
    const int bh = blockIdx.y;
    const int b = bh >> 4, h = bh & 15;
    const int q0 = blockIdx.x * ATQ;

    const size_t hbase = (size_t)(b * NH + h) * SEQ;

    // ---- Q fragments (fp16); wave owns rows w*32..w*32+31 ----
    half8 qf[2][4];
    #pragma unroll
    for (int i = 0; i < 2; i++) {
        const size_t row = hbase + q0 + w * 32 + i * 16 + fm;
        #pragma unroll
        for (int kc = 0; kc < 4; kc++)
            qf[i][kc] = *(const half8*)&Qf[row * 128 + kc * 32 + quad * 8];
    }

    floatx4 oacc[2][8];
    #pragma unroll
    for (int i = 0; i < 2; i++)
        #pragma unroll
        for (int df = 0; df < 8; df++)
            oacc[i][df] = (floatx4){0.f, 0.f, 0.f, 0.f};
    float m_[2][4], l_[2][4];
    #pragma unroll
    for (int i = 0; i < 2; i++)
        #pragma unroll
        for (int r = 0; r < 4; r++) { m_[i][r] = -1e30f; l_[i][r] = 0.f; }

    const unsigned short* gk0  = Kf + hbase * 128;
    const unsigned short* gvt0 = Vt + (size_t)bh * 32 * 8192;

    // staging: 32 chunks of 1 KB (Ks 16, Vts 16); wave w -> chunks w*4..w*4+3
    const int ch0 = w * 4;

    // ---- prologue: stage tile 0 into buffer 0 ----
    #pragma unroll
    for (int c = 0; c < 4; c++) {
        const int ch = ch0 + c;
        const size_t go = (size_t)(ch & 15) * 512 + lane * 8;
        if (ch < 16) async_load16(gk0  + go, (char*)Ks[0]  + ch * 1024);
        else         async_load16(gvt0 + go, (char*)Vts[0] + (ch - 16) * 1024);
    }
    __syncthreads();   // drain: tile 0 staged

    for (int ktile = 0; ktile < SEQ / ATK; ktile++) {
        const int cur = ktile & 1;

        // ---- prefetch tile t+1 into other buffer (drained by end-of-tile barrier) ----
        if (ktile + 1 < SEQ / ATK) {
            const unsigned short* gk  = gk0  + (size_t)(ktile + 1) * ATK * 128;
            const unsigned short* gvt = gvt0 + (size_t)(ktile + 1) * 8192;
            #pragma unroll
            for (int c = 0; c < 4; c++) {
                const int ch = ch0 + c;
                const size_t go = (size_t)(ch & 15) * 512 + lane * 8;
                if (ch < 16) async_load16(gk  + go, (char*)Ks[1 - cur]  + ch * 1024);
                else         async_load16(gvt + go, (char*)Vts[1 - cur] + (ch - 16) * 1024);
            }
        }

        // ---- S = Q K^T (single-term fp16) from buffer cur ----
        floatx4 sacc[2][4];
        #pragma unroll
        for (int i = 0; i < 2; i++)
            #pragma unroll
            for (int jf = 0; jf < 4; jf++)
                sacc[i][jf] = (floatx4){0.f, 0.f, 0.f, 0.f};
        #pragma unroll
        for (int kc = 0; kc < 4; kc++)
            #pragma unroll
            for (int jf = 0; jf < 4; jf++) {
                const int koff = (jf * 16 + fm) * 128 + (((kc * 4 + quad) ^ fm) << 3);
                half8 k8 = *(const half8*)&Ks[cur][koff];
                #pragma unroll
                for (int i = 0; i < 2; i++)
                    sacc[i][jf] = __builtin_amdgcn_mfma_f32_16x16x32_f16(qf[i][kc], k8, sacc[i][jf], 0, 0, 0);
            }

        // ---- online softmax (registers) ----
        float alpha_[2][4];
        #pragma unroll
        for (int i = 0; i < 2; i++)
            #pragma unroll
            for (int r = 0; r < 4; r++) {
                float mx = fmaxf(fmaxf(sacc[i][0][r], sacc[i][1][r]),
                                 fmaxf(sacc[i][2][r], sacc[i][3][r]));
                mx = fmaxf(mx, __shfl_xor(mx, 1));
                mx = fmaxf(mx, __shfl_xor(mx, 2));
                mx = fmaxf(mx, __shfl_xor(mx, 4));
                mx = fmaxf(mx, __shfl_xor(mx, 8));
                const float mold = m_[i][r];
                const float mnew = fmaxf(mold, mx);
                const float al = __expf(mold - mnew);
                m_[i][r] = mnew;
                alpha_[i][r] = al;
                float rs = 0.f;
                #pragma unroll
                for (int jf = 0; jf < 4; jf++) {
                    float p = __expf(sacc[i][jf][r] - mnew);
                    sacc[i][jf][r] = p;
                    rs += p;
                }
                rs += __shfl_xor(rs, 1);
                rs += __shfl_xor(rs, 2);
                rs += __shfl_xor(rs, 4);
                rs += __shfl_xor(rs, 8);
                l_[i][r] = l_[i][r] * al + rs;
            }
        #pragma unroll
        for (int i = 0; i < 2; i++)
            #pragma unroll
            for (int df = 0; df < 8; df++)
                #pragma unroll
                for (int r = 0; r < 4; r++)
                    oacc[i][df][r] *= alpha_[i][r];

        // ---- P -> fp16 into Ps (own rows; wave-local ordering, no barrier) ----
        #pragma unroll
        for (int i = 0; i < 2; i++)
            #pragma unroll
            for (int jf = 0; jf < 4; jf++)
                #pragma unroll
                for (int r = 0; r < 4; r++) {
                    const int row = w * 32 + i * 16 + quad * 4 + r;
                    const int chunk = jf * 2 + (fm >> 3);
                    const int colp = ((chunk ^ (row & 7)) << 3) | (fm & 7);
                    Ps[row * 64 + colp] = fp16_bits(sacc[i][jf][r]);
                }

        // ---- O += P V from buffer cur (fp16) ----
        #pragma unroll
        for (int kc2 = 0; kc2 < 2; kc2++) {
            half8 ap[2];
            #pragma unroll
            for (int i = 0; i < 2; i++) {
                const int row = w * 32 + i * 16 + fm;
                ap[i] = *(const half8*)&Ps[row * 64 + (((kc2 * 4 + quad) ^ (row & 7)) << 3)];
            }
            #pragma unroll
            for (int df = 0; df < 8; df++) {
                const int d = df * 16 + fm;
                half8 bv = *(const half8*)&Vts[cur][d * 64 + (((kc2 * 4 + quad) ^ (d & 7)) << 3)];
                #pragma unroll
                for (int i = 0; i < 2; i++)
                    oacc[i][df] = __builtin_amdgcn_mfma_f32_16x16x32_f16(ap[i], bv, oacc[i][df], 0, 0, 0);
            }
        }

        // single barrier per tile: drains prefetch + protects buffer swap
        __syncthreads();
    }

    // ---- epilogue: AO bf16 [b,s,h,d] ----
    const size_t obase = ((size_t)b * SEQ * NH + h) * HD;
    const size_t rstr = (size_t)NH * HD;
    float linv[2][4];
    #pragma unroll
    for (int i = 0; i < 2; i++)
        #pragma unroll
        for (int r = 0; r < 4; r++) linv[i][r] = 1.0f / l_[i][r];
    #pragma unroll
    for (int i = 0; i < 2; i++)
        #pragma unroll
        for (int df = 0; df < 8; df++)
            #pragma unroll
            for (int r = 0; r < 4; r++) {
                const int row = q0 + w * 32 + i * 16 + quad * 4 + r;
                const int d = df * 16 + fm;
                AO[obase + (size_t)row * rstr + d] = __float2bfloat16(oacc[i][df][r] * linv[i][r]);
            }
}

// ======================= launch =======================
extern "C" void kernel_launch(void* const* d_in, const int* in_sizes, int n_in,
                              void* d_out, int out_size, void* d_ws, size_t ws_size,
                              hipStream_t stream) {
    const float* x  = (const float*)d_in[0];
    const float* wq = (const float*)d_in[1];
    const float* wk = (const float*)d_in[2];
    const float* wv = (const float*)d_in[3];
    const float* wo = (const float*)d_in[4];
    const float* q_scale = (const float*)d_in[5];
    const float* k_scale = (const float*)d_in[6];
    float* out = (float*)d_out;

    const size_t T = (size_t)BATCH * SEQ * NH * HD;   // 8388608
    const size_t W = (size_t)EMB * NH * HD;           // 4194304

    unsigned short* xf   = (unsigned short*)d_ws;     // fp16 x
    unsigned short* aob  = xf + T;                    // bf16 attn out
    unsigned short* Qf   = aob + T;                   // fp16 Q (head-major)
    unsigned short* Kf   = Qf + T;                    // fp16 K (head-major, swizzled)
    unsigned short* Vtb  = Kf + T;                    // fp16 Vt tiles
    unsigned short* wqF  = Vtb + T;                   // fp16 [n][k]
    unsigned short* wkF  = wqF + W;
    unsigned short* wvF  = wkF + W;
    unsigned short* woT  = wvF + W;                   // bf16 [n][k]

    const int M = BATCH * SEQ;   // 4096
    const int N = NH * HD;       // 2048
    const int K = EMB;           // 2048

    // weight transposes (wq/wk/wv->fp16, wo->bf16) + x->fp16 cast, one dispatch
    prep_all<<<dim3(64, 64, 5), dim3(32, 8), 0, stream>>>(
        wq, wk, wv, wo, x, wqF, wkF, wvF, woT, xf);

    // fused Q+K projection: one block computes both tiles from shared A staging
    gemm_qk_fused<<<512, 512, 0, stream>>>(
        xf, wqF, wkF, q_scale, k_scale, Qf, Kf, K);
    // V projection with fused Vt-transpose epilogue
    gemm_v_vt<<<dim3(N / GT, M / GT), 256, 0, stream>>>(xf, wvF, Vtb, K);

    attn14<<<dim3(SEQ / ATQ, BATCH * NH), 512, 0, stream>>>(Qf, Kf, Vtb, (__hip_bfloat16*)aob);

    // out projection with XCD chunk swizzle (same 512-block grid shape as qk_fused)
    gemm_out<<<512, 256, 0, stream>>>(aob, woT, out, M, EMB, NH * HD);
}